// Round 21
// baseline (1508.986 us; speedup 1.0000x reference)
//
#include <hip/hip_runtime.h>
#include <hip/hip_bf16.h>

#define T_    2048
#define H_    2048
#define NQ_   32
#define NKV_  4
#define D_    128
#define E_    64
#define TK_   8
#define I_    768
#define CAP_  512
#define QKVW_ 5120

typedef float  f32x4  __attribute__((ext_vector_type(4)));
typedef __bf16 bf16x8 __attribute__((ext_vector_type(8)));
typedef int    i32x4  __attribute__((ext_vector_type(4)));
#define AS1 __attribute__((address_space(1)))
#define AS3 __attribute__((address_space(3)))

static __device__ __forceinline__ unsigned f2bf_u(float f){
  unsigned u = __builtin_bit_cast(unsigned, f);
  u += 0x7fffu + ((u >> 16) & 1u);
  return u >> 16;
}
static __device__ __forceinline__ float bf2f(unsigned h){
  unsigned u = h << 16;
  return __builtin_bit_cast(float, u);
}
struct HL { int h; int l; };
// split fp32 pair (a,b) -> packed hi word + packed lo word (bf16 each)
static __device__ __forceinline__ HL packsplit(float a, float b){
  unsigned ah = f2bf_u(a), bh = f2bf_u(b);
  float al = a - bf2f(ah), bl = b - bf2f(bh);
  HL r;
  r.h = (int)(ah | (bh << 16));
  r.l = (int)(f2bf_u(al) | (f2bf_u(bl) << 16));
  return r;
}
static __device__ __forceinline__ f32x4 mfma16(bf16x8 a, bf16x8 b, f32x4 c){
  return __builtin_amdgcn_mfma_f32_16x16x32_bf16(a, b, c, 0, 0, 0);
}

// ---------------- RMSNorm (fp32 in -> bf16 hi/lo out, optional fp32 copy) ----
__global__ __launch_bounds__(256) void k_rms(const float* __restrict__ in,
                                             const float* __restrict__ w,
                                             unsigned short* __restrict__ outh,
                                             unsigned short* __restrict__ outl,
                                             float* __restrict__ cpy)
{
  const int t = blockIdx.x, tid = threadIdx.x;
  const float* row = in + (long)t * H_;
  float4 a = *(const float4*)(row + tid*8);
  float4 b = *(const float4*)(row + tid*8 + 4);
  float ss = a.x*a.x + a.y*a.y + a.z*a.z + a.w*a.w
           + b.x*b.x + b.y*b.y + b.z*b.z + b.w*b.w;
  #pragma unroll
  for (int o = 32; o >= 1; o >>= 1) ss += __shfl_xor(ss, o);
  __shared__ float red[4];
  if ((tid & 63) == 0) red[tid >> 6] = ss;
  __syncthreads();
  float tot = red[0] + red[1] + red[2] + red[3];
  float rs = rsqrtf(tot * (1.0f / (float)H_) + 1e-6f);
  const float* wp = w + tid*8;
  float vv[8] = {a.x, a.y, a.z, a.w, b.x, b.y, b.z, b.w};
  i32x4 oh, ol;
  #pragma unroll
  for (int d = 0; d < 4; d++){
    float v0 = vv[2*d]   * rs * wp[2*d];
    float v1 = vv[2*d+1] * rs * wp[2*d+1];
    HL r = packsplit(v0, v1);
    oh[d] = r.h; ol[d] = r.l;
  }
  *(i32x4*)(outh + (long)t * H_ + tid*8) = oh;
  if (outl) *(i32x4*)(outl + (long)t * H_ + tid*8) = ol;
  if (cpy){
    *(float4*)(cpy + (long)t * H_ + tid*8)     = a;
    *(float4*)(cpy + (long)t * H_ + tid*8 + 4) = b;
  }
}

// ---------------- RoPE cos/sin table (accurate sinf/cosf) --------------------
__global__ __launch_bounds__(64) void k_ropetab(const int* __restrict__ pos,
                                                float* __restrict__ cosb,
                                                float* __restrict__ sinb)
{
  int t = blockIdx.x, j = threadIdx.x; // j in 0..63
  float p = (float)pos[t];
  float freq = expf(-(float)j * (2.0f / (float)D_) * 9.210340371976184f);
  float ang = p * freq;
  cosb[t*64 + j] = cosf(ang);
  sinb[t*64 + j] = sinf(ang);
}

// ---------------- q/k RMSNorm + RoPE -> bf16 hi/lo ---------------------------
__global__ __launch_bounds__(256) void k_qknorm(const float* __restrict__ qkv,
                                                const float* __restrict__ qw,
                                                const float* __restrict__ kw,
                                                const float* __restrict__ cosb,
                                                const float* __restrict__ sinb,
                                                unsigned short* __restrict__ qh,
                                                unsigned short* __restrict__ ql,
                                                unsigned short* __restrict__ khp,
                                                unsigned short* __restrict__ klp)
{
  int gw = blockIdx.x*4 + (threadIdx.x >> 6);
  int lane = threadIdx.x & 63;
  int t = gw / 36, hh = gw - t*36;
  const float* src; const float* w;
  unsigned short *dh, *dl;
  if (hh < NQ_){
    src = qkv + (long)t*QKVW_ + hh*D_;
    w = qw;
    dh = qh + ((long)t*NQ_ + hh)*D_;
    dl = ql + ((long)t*NQ_ + hh)*D_;
  } else {
    int kh = hh - NQ_;
    src = qkv + (long)t*QKVW_ + NQ_*D_ + kh*D_;
    w = kw;
    dh = khp + ((long)t*NKV_ + kh)*D_;
    dl = klp + ((long)t*NKV_ + kh)*D_;
  }
  float a = src[lane], b = src[lane + 64];
  float ss = a*a + b*b;
  #pragma unroll
  for (int o = 32; o >= 1; o >>= 1) ss += __shfl_xor(ss, o);
  float rs = rsqrtf(ss * (1.0f / (float)D_) + 1e-6f);
  a *= rs * w[lane];
  b *= rs * w[lane + 64];
  float c = cosb[t*64 + lane], s = sinb[t*64 + lane];
  float r0 = a*c - b*s;
  float r1 = b*c + a*s;
  unsigned h0 = f2bf_u(r0), h1 = f2bf_u(r1);
  dh[lane]      = (unsigned short)h0;
  dh[lane + 64] = (unsigned short)h1;
  dl[lane]      = (unsigned short)f2bf_u(r0 - bf2f(h0));
  dl[lane + 64] = (unsigned short)f2bf_u(r1 - bf2f(h1));
}

// ---------------- V transpose: qkv fp32 -> vt hi/lo [hkv*D][T] ---------------
__global__ __launch_bounds__(256) void k_vtrans(const float* __restrict__ qkv,
                                                unsigned short* __restrict__ vth,
                                                unsigned short* __restrict__ vtl)
{
  __shared__ unsigned short tileh[64][136];
  __shared__ unsigned short tilel[64][136];
  const int t0 = blockIdx.x * 64;
  const int hv = blockIdx.y;
  const int tid = threadIdx.x;
  #pragma unroll
  for (int it = 0; it < 8; it++){
    int chunk = tid + it*256;     // 0..2047
    int r  = chunk >> 5;          // t-row 0..63
    int c4 = chunk & 31;          // float4 col
    float4 v = *(const float4*)(qkv + (long)(t0 + r)*QKVW_ + (NQ_+NKV_)*D_ + hv*D_ + c4*4);
    float vals[4] = {v.x, v.y, v.z, v.w};
    #pragma unroll
    for (int q = 0; q < 4; q++){
      unsigned hi = f2bf_u(vals[q]);
      tileh[r][c4*4+q] = (unsigned short)hi;
      tilel[r][c4*4+q] = (unsigned short)f2bf_u(vals[q] - bf2f(hi));
    }
  }
  __syncthreads();
  int d = tid >> 1, hf = tid & 1;
  long dbase = ((long)(hv*D_ + d))*T_ + t0 + hf*32;
  #pragma unroll
  for (int k = 0; k < 4; k++){
    i32x4 oh, ol;
    #pragma unroll
    for (int d2 = 0; d2 < 4; d2++){
      int r0 = hf*32 + k*8 + d2*2, r1 = r0 + 1;
      oh[d2] = (int)((unsigned)tileh[r0][d] | ((unsigned)tileh[r1][d] << 16));
      ol[d2] = (int)((unsigned)tilel[r0][d] | ((unsigned)tilel[r1][d] << 16));
    }
    *(i32x4*)(vth + dbase + k*8) = oh;
    *(i32x4*)(vtl + dbase + k*8) = ol;
  }
}

// ---------------- Flash attention v7: V-prefetch ping-pong -------------------
#define VISSUE(G, BUF) { \
  const int kst_ = (G) >> 2, dp_ = (G) & 3; \
  _Pragma("unroll") \
  for (int dd = 0; dd < 2; dd++){ \
    int dn_ = dp_*2 + dd; \
    long voff = ((long)(hk*D_ + dn_*16 + l15))*T_ + kv0 + kst_*32 + g16*8; \
    BUF[dd*2]   = *(const bf16x8*)(vth + voff); \
    BUF[dd*2+1] = *(const bf16x8*)(vtl + voff); \
  } }
#define VPV(G, BUF) { \
  const int kst_ = (G) >> 2, dp_ = (G) & 3; \
  _Pragma("unroll") \
  for (int dd = 0; dd < 2; dd++){ \
    int dn_ = dp_*2 + dd; \
    o[dn_] = mfma16(pah[kst_], BUF[dd*2+1], o[dn_]); \
    o[dn_] = mfma16(pal[kst_], BUF[dd*2],   o[dn_]); \
    o[dn_] = mfma16(pah[kst_], BUF[dd*2],   o[dn_]); \
  } }

__global__ __launch_bounds__(256,2) void k_attn(const unsigned short* __restrict__ qbh,
                                                const unsigned short* __restrict__ qbl,
                                                const unsigned short* __restrict__ kbh,
                                                const unsigned short* __restrict__ kbl,
                                                const unsigned short* __restrict__ vth,
                                                const unsigned short* __restrict__ vtl,
                                                unsigned short* __restrict__ abh,
                                                unsigned short* __restrict__ abl)
{
  __shared__ char ldsK[2][2][16384];   // [buf][hi/lo][64 rows x 256B]
  const int b   = blockIdx.x;          // 0..511
  const int xcd = b & 7, kk = xcd >> 1;
  const int s_  = ((b >> 3) << 1) | (xcd & 1);       // 0..127
  const int h   = kk*8 + (s_ >> 4);                  // head
  const int p   = s_ & 15;                           // pair index 0..15
  const int hk  = kk;
  const int tid = threadIdx.x;
  const int wv  = tid >> 6, lane = tid & 63;
  const int l15 = lane & 15, g16 = lane >> 4;
  const float sc = 0.08838834764831845f; // 1/sqrt(128)

  long gb[4];
  #pragma unroll
  for (int i = 0; i < 4; i++){
    int srow = i*16 + (tid >> 4);
    int c = (tid & 15) ^ (srow & 7);
    gb[i] = ((long)srow*NKV_ + hk)*D_ + c*8;
  }

  for (int ph = 0; ph < 2; ph++){
    const int qt  = ph ? p : (31 - p);
    const int q0  = qt*64 + wv*16;
    const int ntB = qt + 1;

    bf16x8 qfh[4], qfl[4];
    {
      long qoff = ((long)(q0 + l15)*NQ_ + h)*D_ + g16*8;
      #pragma unroll
      for (int ks = 0; ks < 4; ks++){
        qfh[ks] = *(const bf16x8*)(qbh + qoff + ks*32);
        qfl[ks] = *(const bf16x8*)(qbl + qoff + ks*32);
      }
    }

    f32x4 zz = {0.f,0.f,0.f,0.f};
    f32x4 o[8];
    #pragma unroll
    for (int dn = 0; dn < 8; dn++) o[dn] = zz;
    float m_run = -1e30f, l_run = 0.f;

    __syncthreads();   // previous phase's LDS reads complete before restaging
    #pragma unroll
    for (int i = 0; i < 4; i++){
      __builtin_amdgcn_global_load_lds((const AS1 int*)(kbh + gb[i]),
          (AS3 int*)((AS3 char*)&ldsK[0][0][0] + i*4096 + tid*16), 16, 0, 0);
      __builtin_amdgcn_global_load_lds((const AS1 int*)(kbl + gb[i]),
          (AS3 int*)((AS3 char*)&ldsK[0][1][0] + i*4096 + tid*16), 16, 0, 0);
    }

    for (int t = 0; t < ntB; t++){
      __syncthreads();                       // drains vmcnt: tile t resident
      const int kv0 = t*64;
      if (t+1 < ntB){
        long kadd = (long)(t+1)*64*NKV_*D_;
        int nb = (t+1) & 1;
        #pragma unroll
        for (int i = 0; i < 4; i++){
          __builtin_amdgcn_global_load_lds((const AS1 int*)(kbh + gb[i] + kadd),
              (AS3 int*)((AS3 char*)&ldsK[nb][0][0] + i*4096 + tid*16), 16, 0, 0);
          __builtin_amdgcn_global_load_lds((const AS1 int*)(kbl + gb[i] + kadd),
              (AS3 int*)((AS3 char*)&ldsK[nb][1][0] + i*4096 + tid*16), 16, 0, 0);
        }
      }
      {
        const char* Kh = &ldsK[t & 1][0][0];
        const char* Kl = &ldsK[t & 1][1][0];
        f32x4 sA[4];
        #pragma unroll
        for (int sub = 0; sub < 4; sub++) sA[sub] = zz;
        __builtin_amdgcn_s_setprio(1);
        #pragma unroll
        for (int sub = 0; sub < 4; sub++){
          int row = sub*16 + l15;
          int rsw = (row & 7) << 4;
          #pragma unroll
          for (int ks = 0; ks < 4; ks++){
            bf16x8 kh = *(const bf16x8*)(Kh + row*256 + (((ks*4 + g16)*16) ^ rsw));
            bf16x8 kl = *(const bf16x8*)(Kl + row*256 + (((ks*4 + g16)*16) ^ rsw));
            sA[sub] = mfma16(kh, qfl[ks], sA[sub]);
            sA[sub] = mfma16(kl, qfh[ks], sA[sub]);
            sA[sub] = mfma16(kh, qfh[ks], sA[sub]);
          }
        }
        __builtin_amdgcn_s_setprio(0);
        bf16x8 vA[4], vB[4];
        VISSUE(0, vA);
        {
          int qrow = q0 + l15;
          float mt = -1e30f;
          #pragma unroll
          for (int sub = 0; sub < 4; sub++)
            #pragma unroll
            for (int r = 0; r < 4; r++){
              int kva = kv0 + sub*16 + g16*4 + r;
              float v = sA[sub][r]*sc;
              if (kva > qrow) v = -1e30f;
              sA[sub][r] = v;
              mt = fmaxf(mt, v);
            }
          mt = fmaxf(mt, __shfl_xor(mt,16));
          mt = fmaxf(mt, __shfl_xor(mt,32));
          float mnew = fmaxf(m_run, mt);
          float corr = __expf(m_run - mnew);
          float ps = 0.f;
          #pragma unroll
          for (int sub = 0; sub < 4; sub++)
            #pragma unroll
            for (int r = 0; r < 4; r++){
              float e = __expf(sA[sub][r] - mnew);
              sA[sub][r] = e;
              ps += e;
            }
          ps += __shfl_xor(ps,16);
          ps += __shfl_xor(ps,32);
          l_run = l_run*corr + ps;
          m_run = mnew;
          #pragma unroll
          for (int r = 0; r < 4; r++){
            float cr = __shfl(corr, g16*4 + r);
            #pragma unroll
            for (int dn = 0; dn < 8; dn++) o[dn][r] *= cr;
          }
        }
        bf16x8 pah[2], pal[2];
        #pragma unroll
        for (int kst = 0; kst < 2; kst++){
          f32x4 s0 = sA[2*kst], s1 = sA[2*kst+1];
          i32x4 pkh, pkl;
          #pragma unroll
          for (int d = 0; d < 4; d++){
            const int e0 = 2*d, e1 = 2*d+1;
            int src0 = (((2*g16 + (e0>>2)) & 3) << 4) | l15;
            int src1 = (((2*g16 + (e1>>2)) & 3) << 4) | l15;
            float a0t = __shfl(s0[e0&3], src0), a1t = __shfl(s1[e0&3], src0);
            float b0t = __shfl(s0[e1&3], src1), b1t = __shfl(s1[e1&3], src1);
            float va = (g16 >= 2) ? a1t : a0t;
            float vb = (g16 >= 2) ? b1t : b0t;
            HL r = packsplit(va, vb);
            pkh[d] = r.h; pkl[d] = r.l;
          }
          pah[kst] = __builtin_bit_cast(bf16x8, pkh);
          pal[kst] = __builtin_bit_cast(bf16x8, pkl);
        }
        VISSUE(1, vB);
        __builtin_amdgcn_s_setprio(1);
        VPV(0, vA); VISSUE(2, vA);
        VPV(1, vB); VISSUE(3, vB);
        VPV(2, vA); VISSUE(4, vA);
        VPV(3, vB); VISSUE(5, vB);
        VPV(4, vA); VISSUE(6, vA);
        VPV(5, vB); VISSUE(7, vB);
        VPV(6, vA);
        VPV(7, vB);
        __builtin_amdgcn_s_setprio(0);
      }
    }

    {
      float linv = 1.0f / l_run;
      #pragma unroll
      for (int r = 0; r < 4; r++){
        float lr = __shfl(linv, g16*4 + r);
        long row = q0 + g16*4 + r;
        #pragma unroll
        for (int dn = 0; dn < 8; dn++){
          float v = o[dn][r]*lr;
          unsigned hi = f2bf_u(v);
          long idx = row*(NQ_*D_) + h*D_ + dn*16 + l15;
          abh[idx] = (unsigned short)hi;
          abl[idx] = (unsigned short)f2bf_u(v - bf2f(hi));
        }
      }
    }
  }
}

// ---------------- Split-precision GEMM (A hi/lo bf16 x B fp32) ---------------
// MODE 0: qkv proj (store fp32)   MODE 1: wo proj (+residual, store fp32)
struct SA {
  const unsigned short* Ah;
  const unsigned short* Al;
  const float* B;
  int lda, ldb, K, ldc;
  float* Cf;
  const float* add;
};

template<int MODE>
__global__ __launch_bounds__(256,2) void k_gs(SA ga)
{
  __shared__ unsigned short ldsAh[128*64];
  __shared__ unsigned short ldsAl[128*64];
  __shared__ unsigned short ldsBh[8*128*8];
  __shared__ unsigned short ldsBl[8*128*8];
  const int tid = threadIdx.x;
  const int lane = tid & 63;
  const int wv = tid >> 6;
  const int wm = (wv >> 1)*64, wn = (wv & 1)*64;
  const int l15 = lane & 15, g16 = lane >> 4;

  const long m0 = (long)blockIdx.y * 128;
  const long n0 = (long)blockIdx.x * 128;

  long aoff[4];
  #pragma unroll
  for (int i = 0; i < 4; i++){
    int chunk = tid + i*256;
    int m = chunk >> 3, c = chunk & 7;
    aoff[i] = (m0 + m) * (long)ga.lda + c*8;
  }
  const float* brow = ga.B + n0 + (long)((tid >> 5)*8) * ga.ldb + (tid & 31)*4;

  f32x4 zz = {0.f,0.f,0.f,0.f};
  f32x4 acc[4][4];
  #pragma unroll
  for (int i = 0; i < 4; i++)
    #pragma unroll
    for (int j = 0; j < 4; j++) acc[i][j] = zz;

  i32x4 pva[4], pvl[4];
  float4 pb[8];
  #pragma unroll
  for (int i = 0; i < 4; i++){
    pva[i] = *(const i32x4*)(ga.Ah + aoff[i]);
    pvl[i] = *(const i32x4*)(ga.Al + aoff[i]);
  }
  #pragma unroll
  for (int r = 0; r < 8; r++) pb[r] = *(const float4*)(brow + (long)r * ga.ldb);

  for (int kt = 0; kt < ga.K; kt += 64){
    __syncthreads();
    #pragma unroll
    for (int i = 0; i < 4; i++){
      int chunk = tid + i*256;
      int m = chunk >> 3, c = chunk & 7;
      int sw = (c*16) ^ ((m & 7) << 4);
      *(i32x4*)((char*)ldsAh + m*128 + sw) = pva[i];
      *(i32x4*)((char*)ldsAl + m*128 + sw) = pvl[i];
    }
    {
      i32x4 ph0, ph1, ph2, ph3, pl0, pl1, pl2, pl3;
      #pragma unroll
      for (int r = 0; r < 8; r += 2){
        float4 va = pb[r];
        float4 vb = pb[r+1];
        int d = r >> 1;
        HL rx = packsplit(va.x, vb.x); ph0[d] = rx.h; pl0[d] = rx.l;
        HL ry = packsplit(va.y, vb.y); ph1[d] = ry.h; pl1[d] = ry.l;
        HL rz = packsplit(va.z, vb.z); ph2[d] = rz.h; pl2[d] = rz.l;
        HL rw = packsplit(va.w, vb.w); ph3[d] = rw.h; pl3[d] = rw.l;
      }
      int kbb = tid >> 5, nb = (tid & 31)*4;
      long bo = ((long)kbb*128 + nb) << 4;
      char* bph = (char*)ldsBh + bo;
      char* bpl = (char*)ldsBl + bo;
      *(i32x4*)(bph)      = ph0;  *(i32x4*)(bpl)      = pl0;
      *(i32x4*)(bph + 16) = ph1;  *(i32x4*)(bpl + 16) = pl1;
      *(i32x4*)(bph + 32) = ph2;  *(i32x4*)(bpl + 32) = pl2;
      *(i32x4*)(bph + 48) = ph3;  *(i32x4*)(bpl + 48) = pl3;
    }
    __syncthreads();
    if (kt + 64 < ga.K){
      #pragma unroll
      for (int i = 0; i < 4; i++){
        pva[i] = *(const i32x4*)(ga.Ah + aoff[i] + kt + 64);
        pvl[i] = *(const i32x4*)(ga.Al + aoff[i] + kt + 64);
      }
      #pragma unroll
      for (int r = 0; r < 8; r++) pb[r] = *(const float4*)(brow + (long)(kt + 64 + r) * ga.ldb);
    }
    #pragma unroll
    for (int ks = 0; ks < 2; ks++){
      bf16x8 afh[4], afl[4], bfh[4], bfl[4];
      #pragma unroll
      for (int i = 0; i < 4; i++){
        int m = wm + i*16 + l15;
        int sw = (ks*64 + g16*16) ^ ((m & 7) << 4);
        afh[i] = *(const bf16x8*)((const char*)ldsAh + m*128 + sw);
        afl[i] = *(const bf16x8*)((const char*)ldsAl + m*128 + sw);
      }
      #pragma unroll
      for (int j = 0; j < 4; j++){
        int n = wn + j*16 + l15;
        long bo = ((long)(ks*4 + g16)*128 + n) << 4;
        bfh[j] = *(const bf16x8*)((const char*)ldsBh + bo);
        bfl[j] = *(const bf16x8*)((const char*)ldsBl + bo);
      }
      #pragma unroll
      for (int i = 0; i < 4; i++)
        #pragma unroll
        for (int j = 0; j < 4; j++){
          acc[i][j] = mfma16(afh[i], bfl[j], acc[i][j]);
          acc[i][j] = mfma16(afl[i], bfh[j], acc[i][j]);
          acc[i][j] = mfma16(afh[i], bfh[j], acc[i][j]);
        }
    }
  }

  #pragma unroll
  for (int i = 0; i < 4; i++){
    #pragma unroll
    for (int j = 0; j < 4; j++){
      #pragma unroll
      for (int r = 0; r < 4; r++){
        float v = acc[i][j][r];
        long grow = m0 + wm + i*16 + g16*4 + r;
        long gcol = n0 + wn + j*16 + l15;
        long idx = grow * ga.ldc + gcol;
        if (MODE == 0) ga.Cf[idx] = v;
        else           ga.Cf[idx] = v + ga.add[idx];
      }
    }
  }
}

// ---------------- Router logits: split-bf16 GEMM M=2048 N=64 K=2048 ----------
__global__ __launch_bounds__(256,2) void k_logits(const unsigned short* __restrict__ Ah,
                                                  const unsigned short* __restrict__ Al,
                                                  const float* __restrict__ B,
                                                  float* __restrict__ logits)
{
  __shared__ unsigned short ldsAh[256*64];   // 32 KB
  __shared__ unsigned short ldsAl[256*64];   // 32 KB
  __shared__ unsigned short ldsBh[8*64*8];   // 8 KB
  __shared__ unsigned short ldsBl[8*64*8];   // 8 KB
  const int tid = threadIdx.x, lane = tid & 63, wv = tid >> 6;
  const int l15 = lane & 15, g16 = lane >> 4;
  const long m0 = (long)blockIdx.x * 256;

  long aoff[8];
  #pragma unroll
  for (int i = 0; i < 8; i++){
    int chunk = tid + i*256;
    int m = chunk >> 3, c = chunk & 7;
    int csw = c ^ (m & 7);
    aoff[i] = (m0 + m) * (long)H_ + csw*8;
  }
  const float* brow = B + (long)((tid >> 5)*8) * E_ + (tid & 31)*2;

  f32x4 zz = {0.f,0.f,0.f,0.f};
  f32x4 acc[4][4];
  #pragma unroll
  for (int i = 0; i < 4; i++)
    #pragma unroll
    for (int j = 0; j < 4; j++) acc[i][j] = zz;

  float2 pb[8];
  #pragma unroll
  for (int r = 0; r < 8; r++) pb[r] = *(const float2*)(brow + (long)r * E_);

  for (int kt = 0; kt < H_; kt += 64){
    __syncthreads();
    #pragma unroll
    for (int i = 0; i < 8; i++){
      __builtin_amdgcn_global_load_lds((const AS1 int*)(Ah + aoff[i] + kt),
          (AS3 int*)((AS3 char*)ldsAh + i*4096 + tid*16), 16, 0, 0);
      __builtin_amdgcn_global_load_lds((const AS1 int*)(Al + aoff[i] + kt),
          (AS3 int*)((AS3 char*)ldsAl + i*4096 + tid*16), 16, 0, 0);
    }
    {
      i32x4 p0h, p0l, p1h, p1l;
      #pragma unroll
      for (int r = 0; r < 8; r += 2){
        int d = r >> 1;
        HL rx = packsplit(pb[r].x, pb[r+1].x); p0h[d] = rx.h; p0l[d] = rx.l;
        HL ry = packsplit(pb[r].y, pb[r+1].y); p1h[d] = ry.h; p1l[d] = ry.l;
      }
      int kbb = tid >> 5, nb = (tid & 31)*2;
      long bo = ((long)kbb*64 + nb) << 4;
      *(i32x4*)((char*)ldsBh + bo)      = p0h;
      *(i32x4*)((char*)ldsBh + bo + 16) = p1h;
      *(i32x4*)((char*)ldsBl + bo)      = p0l;
      *(i32x4*)((char*)ldsBl + bo + 16) = p1l;
    }
    __syncthreads();
    if (kt + 64 < H_){
      #pragma unroll
      for (int r = 0; r < 8; r++) pb[r] = *(const float2*)(brow + (long)(kt + 64 + r) * E_);
    }
    #pragma unroll
    for (int ks = 0; ks < 2; ks++){
      bf16x8 afh[4], afl[4], bfh[4], bfl[4];
      #pragma unroll
      for (int i = 0; i < 4; i++){
        int m = wv*64 + i*16 + l15;
        int sw = (ks*64 + g16*16) ^ ((m & 7) << 4);
        afh[i] = *(const bf16x8*)((const char*)ldsAh + m*128 + sw);
        afl[i] = *(const bf16x8*)((const char*)ldsAl + m*128 + sw);
      }
      #pragma unroll
      for (int j = 0; j < 4; j++){
        int n = j*16 + l15;
        long bo = ((long)(ks*4 + g16)*64 + n) << 4;
        bfh[j] = *(const bf16x8*)((const char*)ldsBh + bo);
        bfl[j] = *(const bf16x8*)((const char*)ldsBl + bo);
      }
      #pragma unroll
      for (int i = 0; i < 4; i++)
        #pragma unroll
        for (int j = 0; j < 4; j++){
          acc[i][j] = mfma16(afh[i], bfl[j], acc[i][j]);
          acc[i][j] = mfma16(afl[i], bfh[j], acc[i][j]);
          acc[i][j] = mfma16(afh[i], bfh[j], acc[i][j]);
        }
    }
  }

  #pragma unroll
  for (int i = 0; i < 4; i++)
    #pragma unroll
    for (int j = 0; j < 4; j++)
      #pragma unroll
      for (int r = 0; r < 4; r++){
        long row = m0 + wv*64 + i*16 + g16*4 + r;
        logits[row*E_ + j*16 + l15] = acc[i][j][r];
      }
}

// ---------------- Router part 2: softmax + top8 from logits ------------------
__global__ __launch_bounds__(64) void k_router2(const float* __restrict__ logits,
                                                int* __restrict__ tidx,
                                                float* __restrict__ twv)
{
  __shared__ int   ti[8];
  __shared__ float tv[8];
  const int t = blockIdx.x, lane = threadIdx.x;
  float acc = logits[(long)t*E_ + lane];
  float mx = acc;
  #pragma unroll
  for (int o = 32; o >= 1; o >>= 1) mx = fmaxf(mx, __shfl_xor(mx, o));
  float p = __expf(acc - mx);
  float sm = p;
  #pragma unroll
  for (int o = 32; o >= 1; o >>= 1) sm += __shfl_xor(sm, o);
  p /= sm;
  float cur = p, wsum = 0.f;
  #pragma unroll
  for (int j = 0; j < 8; j++){
    float v = cur; int ix = lane;
    #pragma unroll
    for (int o = 1; o < 64; o <<= 1){
      float ov = __shfl_xor(v, o); int oi = __shfl_xor(ix, o);
      if (ov > v || (ov == v && oi < ix)){ v = ov; ix = oi; }
    }
    if (lane == ix) cur = -1.f;
    wsum += v;
    if (lane == 0){ ti[j] = ix; tv[j] = v; }
  }
  __syncthreads();
  if (lane < 8){
    tidx[t*TK_ + lane] = ti[lane];
    twv [t*TK_ + lane] = tv[lane] / wsum;
  }
}

// ---------------- Plain bf16 GEMM (MoE), M=256 x N=64, async pipeline --------
// K-step 32; double-buffered LDS for BOTH A (global_load_lds, zero regs) and
// B (bf16, written from an 8-reg fp32 prefetch). ONE barrier per iteration:
// [barrier: tile t resident] -> issue A(t+1) -> write B(t+1) from regs ->
// load B regs(t+2) -> compute(t). A loads get a full compute phase to land
// (was ~50 cy); B reg loads span >1 iteration. LDS 40KB, (256,3).
struct GA {
  const unsigned short* A;
  const float* B;
  const float* B2;
  int lda, ldb, K, ldc;
  unsigned short* Cb;
  const int* rowidx;
  const float* wslot;
  const int* counts;
  float* outp;
};

template<int MODE>
__global__ __launch_bounds__(256,3) void k_gemm(GA ga)
{
  __shared__ unsigned short ldsA[2][256*32];   // 2 x 16 KB
  __shared__ unsigned short ldsB[2][4*64*8];   // 2 x 4 KB
  const int tid = threadIdx.x;
  const int lane = tid & 63;
  const int wv = tid >> 6;
  const int l15 = lane & 15, g16 = lane >> 4;

  long m0 = (long)blockIdx.y * 256;
  long n0 = 0;
  const unsigned short* A = ga.A;
  const int* rowmap = nullptr;
  int e = blockIdx.z, count = ga.counts[e];
  if ((int)m0 >= count) return;

  // B column pointer: thread owns (kb = tid>>6, nb = tid&63)
  const int kb = tid >> 6, nb = tid & 63;
  const float* bcol;
  if (MODE == 2){
    n0 = (long)blockIdx.x * 32;
    rowmap = ga.rowidx + e * CAP_;
    if (nb < 32) bcol = ga.B  + (long)e * H_ * I_ + n0 + nb;
    else         bcol = ga.B2 + (long)e * H_ * I_ + n0 + (nb - 32);
  } else {
    n0 = (long)blockIdx.x * 64;
    bcol = ga.B + (long)e * I_ * H_ + n0 + nb;
    A = ga.A + (long)e * CAP_ * I_;
  }

  // A source pointers, pre-swizzled column (LDS dest linear, chunk = 16B)
  const unsigned short* arow[4];
  #pragma unroll
  for (int i = 0; i < 4; i++){
    int chunk = tid + i*256;
    int m = chunk >> 2, c = chunk & 3;
    int csw = c ^ (m & 3);
    int s = (int)m0 + m; if (s > count - 1) s = count - 1;
    long row = (MODE == 2) ? (long)rowmap[s] : (long)s;
    arow[i] = A + row * (long)ga.lda + csw*8;
  }

  f32x4 zz = {0.f,0.f,0.f,0.f};
  f32x4 acc[4][4];
  #pragma unroll
  for (int i = 0; i < 4; i++)
    #pragma unroll
    for (int j = 0; j < 4; j++) acc[i][j] = zz;

  const int nt = ga.K / 32;
  float pbv[8];

  // prologue: stage A(0); load+convert+write B(0); load pb for tile 1
  #pragma unroll
  for (int i = 0; i < 4; i++){
    __builtin_amdgcn_global_load_lds((const AS1 int*)(arow[i]),
        (AS3 int*)((AS3 char*)&ldsA[0][0] + i*4096 + tid*16), 16, 0, 0);
  }
  #pragma unroll
  for (int j = 0; j < 8; j++) pbv[j] = bcol[(long)(kb*8 + j) * ga.ldb];
  {
    i32x4 p0;
    #pragma unroll
    for (int d = 0; d < 4; d++)
      p0[d] = (int)(f2bf_u(pbv[2*d]) | (f2bf_u(pbv[2*d+1]) << 16));
    *(i32x4*)((char*)&ldsB[0][0] + ((kb*64 + nb) << 4)) = p0;
  }
  if (nt > 1){
    #pragma unroll
    for (int j = 0; j < 8; j++) pbv[j] = bcol[(long)(32 + kb*8 + j) * ga.ldb];
  }

  for (int t = 0; t < nt; t++){
    __syncthreads();   // A(t) resident, B(t) visible, buffers of t-1 free
    if (t+1 < nt){
      const int nbuf = (t+1) & 1;
      const int ktn = (t+1) * 32;
      #pragma unroll
      for (int i = 0; i < 4; i++){
        __builtin_amdgcn_global_load_lds((const AS1 int*)(arow[i] + ktn),
            (AS3 int*)((AS3 char*)&ldsA[nbuf][0] + i*4096 + tid*16), 16, 0, 0);
      }
      i32x4 p0;
      #pragma unroll
      for (int d = 0; d < 4; d++)
        p0[d] = (int)(f2bf_u(pbv[2*d]) | (f2bf_u(pbv[2*d+1]) << 16));
      *(i32x4*)((char*)&ldsB[nbuf][0] + ((kb*64 + nb) << 4)) = p0;
      if (t+2 < nt){
        const int ktn2 = (t+2) * 32;
        #pragma unroll
        for (int j = 0; j < 8; j++) pbv[j] = bcol[(long)(ktn2 + kb*8 + j) * ga.ldb];
      }
    }
    {
      const char* La = (const char*)&ldsA[t & 1][0];
      const char* Lb = (const char*)&ldsB[t & 1][0];
      bf16x8 af[4], bfv[4];
      #pragma unroll
      for (int i = 0; i < 4; i++){
        int m = wv*64 + i*16 + l15;
        af[i] = *(const bf16x8*)(La + m*64 + ((g16*16) ^ ((m & 3) << 4)));
      }
      #pragma unroll
      for (int j = 0; j < 4; j++){
        int n = j*16 + l15;
        bfv[j] = *(const bf16x8*)(Lb + ((g16*64 + n) << 4));
      }
      #pragma unroll
      for (int i = 0; i < 4; i++)
        #pragma unroll
        for (int j = 0; j < 4; j++)
          acc[i][j] = mfma16(af[i], bfv[j], acc[i][j]);
    }
  }

  if (MODE == 2){
    #pragma unroll
    for (int i = 0; i < 4; i++){
      #pragma unroll
      for (int jj = 0; jj < 2; jj++){
        #pragma unroll
        for (int r = 0; r < 4; r++){
          float g = acc[i][jj][r];
          float u = acc[i][jj+2][r];
          float actv = g / (1.f + __expf(-g)) * u;
          int grow = (int)m0 + wv*64 + i*16 + g16*4 + r;
          if (grow < count)
            ga.Cb[((long)e*CAP_ + grow)*I_ + n0 + jj*16 + l15] = (unsigned short)f2bf_u(actv);
        }
      }
    }
  } else {
    #pragma unroll
    for (int i = 0; i < 4; i++){
      #pragma unroll
      for (int j = 0; j < 4; j++){
        #pragma unroll
        for (int r = 0; r < 4; r++){
          float v = acc[i][j][r];
          int grow = (int)m0 + wv*64 + i*16 + g16*4 + r;
          long gcol = n0 + j*16 + l15;
          if (grow < count){
            float ww = ga.wslot[e*CAP_ + grow];
            int tk = ga.rowidx[e*CAP_ + grow];
            atomicAdd(ga.outp + (long)tk*H_ + gcol, v*ww);
          }
        }
      }
    }
  }
}

// ---------------- Capacity scan (reference cumsum order) ---------------------
__global__ __launch_bounds__(64) void k_route(const int* __restrict__ tidx,
                                              const float* __restrict__ twv,
                                              int* __restrict__ rowi,
                                              float* __restrict__ wsl,
                                              int* __restrict__ cnts)
{
  const int e = blockIdx.x, lane = threadIdx.x;
  int run = 0;
  for (int s0 = 0; s0 < T_*TK_; s0 += 64){
    int s = s0 + lane;
    int idx = tidx[s];
    bool m = (idx == e);
    unsigned long long mk = __ballot(m);
    int pre = __popcll(mk & ((1ull << lane) - 1ull));
    int pos = run + pre;
    if (m && pos < CAP_){
      rowi[e*CAP_ + pos] = s >> 3;
      wsl [e*CAP_ + pos] = twv[s];
    }
    run += __popcll(mk);
  }
  if (lane == 0) cnts[e] = (run < CAP_) ? run : CAP_;
}

// ---------------- launch -----------------------------------------------------
extern "C" void kernel_launch(void* const* d_in, const int* in_sizes, int n_in,
                              void* d_out, int out_size, void* d_ws, size_t ws_size,
                              hipStream_t stream)
{
  (void)in_sizes; (void)n_in; (void)out_size; (void)ws_size;
  const float* x    = (const float*)d_in[0];
  const int*   pos  = (const int*)d_in[1];
  const float* wqkv = (const float*)d_in[2];
  const float* wo   = (const float*)d_in[3];
  const float* qnw  = (const float*)d_in[4];
  const float* knw  = (const float*)d_in[5];
  const float* ln1  = (const float*)d_in[6];
  const float* ln2  = (const float*)d_in[7];
  const float* gwt  = (const float*)d_in[8];
  const float* wg   = (const float*)d_in[9];
  const float* wu   = (const float*)d_in[10];
  const float* wd   = (const float*)d_in[11];
  float* out = (float*)d_out;

  char* ws = (char*)d_ws;
  size_t off = 0;
  auto alloc = [&](size_t b)->void*{ void* p = ws + off; off += (b + 255) & ~(size_t)255; return p; };

  unsigned short* hbh = (unsigned short*)alloc((size_t)T_*H_*2);
  unsigned short* hbl = (unsigned short*)alloc((size_t)T_*H_*2);
  float* qkv          = (float*)alloc((size_t)T_*QKVW_*4);
  float* cosb         = (float*)alloc((size_t)T_*64*4);
  float* sinb         = (float*)alloc((size_t)T_*64*4);
  unsigned short* qbh = (unsigned short*)alloc((size_t)T_*NQ_*D_*2);
  unsigned short* qbl = (unsigned short*)alloc((size_t)T_*NQ_*D_*2);
  unsigned short* kbh = (unsigned short*)alloc((size_t)T_*NKV_*D_*2);
  unsigned short* kbl = (unsigned short*)alloc((size_t)T_*NKV_*D_*2);
  unsigned short* vth = (unsigned short*)alloc((size_t)NKV_*D_*T_*2);
  unsigned short* vtl = (unsigned short*)alloc((size_t)NKV_*D_*T_*2);
  unsigned short* abh = (unsigned short*)alloc((size_t)T_*NQ_*D_*2);
  unsigned short* abl = (unsigned short*)alloc((size_t)T_*NQ_*D_*2);
  float* x2           = (float*)alloc((size_t)T_*H_*4);
  unsigned short* h2b = (unsigned short*)alloc((size_t)T_*H_*2);
  unsigned short* h2l = (unsigned short*)alloc((size_t)T_*H_*2);
  float* lgt          = (float*)alloc((size_t)T_*E_*4);
  int* tidx           = (int*)alloc((size_t)T_*TK_*4);
  float* twv          = (float*)alloc((size_t)T_*TK_*4);
  int* rowi           = (int*)alloc((size_t)E_*CAP_*4);
  float* wsl          = (float*)alloc((size_t)E_*CAP_*4);
  int* cnts           = (int*)alloc((size_t)E_*4);
  unsigned short* gu  = (unsigned short*)alloc((size_t)E_*CAP_*I_*2);  // fused act

  k_rms<<<T_, 256, 0, stream>>>(x, ln1, hbh, hbl, nullptr);
  k_ropetab<<<T_, 64, 0, stream>>>(pos, cosb, sinb);
  {
    SA a{}; a.Ah = hbh; a.Al = hbl; a.B = wqkv; a.lda = H_; a.ldb = QKVW_; a.K = H_; a.ldc = QKVW_; a.Cf = qkv;
    k_gs<0><<<dim3(QKVW_/128, T_/128), 256, 0, stream>>>(a);
  }
  k_qknorm<<<T_*36/4, 256, 0, stream>>>(qkv, qnw, knw, cosb, sinb, qbh, qbl, kbh, kbl);
  k_vtrans<<<dim3(T_/64, NKV_), 256, 0, stream>>>(qkv, vth, vtl);
  k_attn<<<512, 256, 0, stream>>>(qbh, qbl, kbh, kbl, vth, vtl, abh, abl);
  {
    SA a{}; a.Ah = abh; a.Al = abl; a.B = wo; a.lda = NQ_*D_; a.ldb = H_; a.K = NQ_*D_; a.ldc = H_;
    a.Cf = x2; a.add = x;
    k_gs<1><<<dim3(H_/128, T_/128), 256, 0, stream>>>(a);
  }
  k_rms<<<T_, 256, 0, stream>>>(x2, ln2, h2b, h2l, out);   // h2 hi/lo + out = x2
  k_logits<<<T_/256, 256, 0, stream>>>(h2b, h2l, gwt, lgt);
  k_router2<<<T_, 64, 0, stream>>>(lgt, tidx, twv);
  k_route<<<E_, 64, 0, stream>>>(tidx, twv, rowi, wsl, cnts);
  {
    GA a{}; a.A = h2b; a.B = wg; a.B2 = wu; a.lda = H_; a.ldb = I_; a.K = H_;
    a.Cb = gu; a.rowidx = rowi; a.counts = cnts;
    k_gemm<2><<<dim3(24, 2, E_), 256, 0, stream>>>(a);
  }
  {
    GA a{}; a.A = gu; a.B = wd; a.lda = I_; a.ldb = H_; a.K = I_;
    a.counts = cnts; a.rowidx = rowi; a.wslot = wsl; a.outp = out;
    k_gemm<3><<<dim3(32, 2, E_), 256, 0, stream>>>(a);
  }
}

// Round 22
// 1437.673 us; speedup vs baseline: 1.0496x; 1.0496x over previous
//
#include <hip/hip_runtime.h>
#include <hip/hip_bf16.h>

#define T_    2048
#define H_    2048
#define NQ_   32
#define NKV_  4
#define D_    128
#define E_    64
#define TK_   8
#define I_    768
#define CAP_  512
#define QKVW_ 5120

typedef float  f32x4  __attribute__((ext_vector_type(4)));
typedef __bf16 bf16x8 __attribute__((ext_vector_type(8)));
typedef int    i32x4  __attribute__((ext_vector_type(4)));
#define AS1 __attribute__((address_space(1)))
#define AS3 __attribute__((address_space(3)))

static __device__ __forceinline__ unsigned f2bf_u(float f){
  unsigned u = __builtin_bit_cast(unsigned, f);
  u += 0x7fffu + ((u >> 16) & 1u);
  return u >> 16;
}
static __device__ __forceinline__ float bf2f(unsigned h){
  unsigned u = h << 16;
  return __builtin_bit_cast(float, u);
}
struct HL { int h; int l; };
// split fp32 pair (a,b) -> packed hi word + packed lo word (bf16 each)
static __device__ __forceinline__ HL packsplit(float a, float b){
  unsigned ah = f2bf_u(a), bh = f2bf_u(b);
  float al = a - bf2f(ah), bl = b - bf2f(bh);
  HL r;
  r.h = (int)(ah | (bh << 16));
  r.l = (int)(f2bf_u(al) | (f2bf_u(bl) << 16));
  return r;
}
static __device__ __forceinline__ f32x4 mfma16(bf16x8 a, bf16x8 b, f32x4 c){
  return __builtin_amdgcn_mfma_f32_16x16x32_bf16(a, b, c, 0, 0, 0);
}

// ---------------- RMSNorm (fp32 in -> bf16 hi/lo out, optional fp32 copy) ----
__global__ __launch_bounds__(256) void k_rms(const float* __restrict__ in,
                                             const float* __restrict__ w,
                                             unsigned short* __restrict__ outh,
                                             unsigned short* __restrict__ outl,
                                             float* __restrict__ cpy)
{
  const int t = blockIdx.x, tid = threadIdx.x;
  const float* row = in + (long)t * H_;
  float4 a = *(const float4*)(row + tid*8);
  float4 b = *(const float4*)(row + tid*8 + 4);
  float ss = a.x*a.x + a.y*a.y + a.z*a.z + a.w*a.w
           + b.x*b.x + b.y*b.y + b.z*b.z + b.w*b.w;
  #pragma unroll
  for (int o = 32; o >= 1; o >>= 1) ss += __shfl_xor(ss, o);
  __shared__ float red[4];
  if ((tid & 63) == 0) red[tid >> 6] = ss;
  __syncthreads();
  float tot = red[0] + red[1] + red[2] + red[3];
  float rs = rsqrtf(tot * (1.0f / (float)H_) + 1e-6f);
  const float* wp = w + tid*8;
  float vv[8] = {a.x, a.y, a.z, a.w, b.x, b.y, b.z, b.w};
  i32x4 oh, ol;
  #pragma unroll
  for (int d = 0; d < 4; d++){
    float v0 = vv[2*d]   * rs * wp[2*d];
    float v1 = vv[2*d+1] * rs * wp[2*d+1];
    HL r = packsplit(v0, v1);
    oh[d] = r.h; ol[d] = r.l;
  }
  *(i32x4*)(outh + (long)t * H_ + tid*8) = oh;
  if (outl) *(i32x4*)(outl + (long)t * H_ + tid*8) = ol;
  if (cpy){
    *(float4*)(cpy + (long)t * H_ + tid*8)     = a;
    *(float4*)(cpy + (long)t * H_ + tid*8 + 4) = b;
  }
}

// ---------------- RoPE cos/sin table (accurate sinf/cosf) --------------------
__global__ __launch_bounds__(64) void k_ropetab(const int* __restrict__ pos,
                                                float* __restrict__ cosb,
                                                float* __restrict__ sinb)
{
  int t = blockIdx.x, j = threadIdx.x; // j in 0..63
  float p = (float)pos[t];
  float freq = expf(-(float)j * (2.0f / (float)D_) * 9.210340371976184f);
  float ang = p * freq;
  cosb[t*64 + j] = cosf(ang);
  sinb[t*64 + j] = sinf(ang);
}

// ---------------- q/k RMSNorm + RoPE -> bf16 hi/lo ---------------------------
__global__ __launch_bounds__(256) void k_qknorm(const float* __restrict__ qkv,
                                                const float* __restrict__ qw,
                                                const float* __restrict__ kw,
                                                const float* __restrict__ cosb,
                                                const float* __restrict__ sinb,
                                                unsigned short* __restrict__ qh,
                                                unsigned short* __restrict__ ql,
                                                unsigned short* __restrict__ khp,
                                                unsigned short* __restrict__ klp)
{
  int gw = blockIdx.x*4 + (threadIdx.x >> 6);
  int lane = threadIdx.x & 63;
  int t = gw / 36, hh = gw - t*36;
  const float* src; const float* w;
  unsigned short *dh, *dl;
  if (hh < NQ_){
    src = qkv + (long)t*QKVW_ + hh*D_;
    w = qw;
    dh = qh + ((long)t*NQ_ + hh)*D_;
    dl = ql + ((long)t*NQ_ + hh)*D_;
  } else {
    int kh = hh - NQ_;
    src = qkv + (long)t*QKVW_ + NQ_*D_ + kh*D_;
    w = kw;
    dh = khp + ((long)t*NKV_ + kh)*D_;
    dl = klp + ((long)t*NKV_ + kh)*D_;
  }
  float a = src[lane], b = src[lane + 64];
  float ss = a*a + b*b;
  #pragma unroll
  for (int o = 32; o >= 1; o >>= 1) ss += __shfl_xor(ss, o);
  float rs = rsqrtf(ss * (1.0f / (float)D_) + 1e-6f);
  a *= rs * w[lane];
  b *= rs * w[lane + 64];
  float c = cosb[t*64 + lane], s = sinb[t*64 + lane];
  float r0 = a*c - b*s;
  float r1 = b*c + a*s;
  unsigned h0 = f2bf_u(r0), h1 = f2bf_u(r1);
  dh[lane]      = (unsigned short)h0;
  dh[lane + 64] = (unsigned short)h1;
  dl[lane]      = (unsigned short)f2bf_u(r0 - bf2f(h0));
  dl[lane + 64] = (unsigned short)f2bf_u(r1 - bf2f(h1));
}

// ---------------- V transpose: qkv fp32 -> vt hi/lo [hkv*D][T] ---------------
__global__ __launch_bounds__(256) void k_vtrans(const float* __restrict__ qkv,
                                                unsigned short* __restrict__ vth,
                                                unsigned short* __restrict__ vtl)
{
  __shared__ unsigned short tileh[64][136];
  __shared__ unsigned short tilel[64][136];
  const int t0 = blockIdx.x * 64;
  const int hv = blockIdx.y;
  const int tid = threadIdx.x;
  #pragma unroll
  for (int it = 0; it < 8; it++){
    int chunk = tid + it*256;     // 0..2047
    int r  = chunk >> 5;          // t-row 0..63
    int c4 = chunk & 31;          // float4 col
    float4 v = *(const float4*)(qkv + (long)(t0 + r)*QKVW_ + (NQ_+NKV_)*D_ + hv*D_ + c4*4);
    float vals[4] = {v.x, v.y, v.z, v.w};
    #pragma unroll
    for (int q = 0; q < 4; q++){
      unsigned hi = f2bf_u(vals[q]);
      tileh[r][c4*4+q] = (unsigned short)hi;
      tilel[r][c4*4+q] = (unsigned short)f2bf_u(vals[q] - bf2f(hi));
    }
  }
  __syncthreads();
  int d = tid >> 1, hf = tid & 1;
  long dbase = ((long)(hv*D_ + d))*T_ + t0 + hf*32;
  #pragma unroll
  for (int k = 0; k < 4; k++){
    i32x4 oh, ol;
    #pragma unroll
    for (int d2 = 0; d2 < 4; d2++){
      int r0 = hf*32 + k*8 + d2*2, r1 = r0 + 1;
      oh[d2] = (int)((unsigned)tileh[r0][d] | ((unsigned)tileh[r1][d] << 16));
      ol[d2] = (int)((unsigned)tilel[r0][d] | ((unsigned)tilel[r1][d] << 16));
    }
    *(i32x4*)(vth + dbase + k*8) = oh;
    *(i32x4*)(vtl + dbase + k*8) = ol;
  }
}

// ---------------- Flash attention v7: V-prefetch ping-pong -------------------
#define VISSUE(G, BUF) { \
  const int kst_ = (G) >> 2, dp_ = (G) & 3; \
  _Pragma("unroll") \
  for (int dd = 0; dd < 2; dd++){ \
    int dn_ = dp_*2 + dd; \
    long voff = ((long)(hk*D_ + dn_*16 + l15))*T_ + kv0 + kst_*32 + g16*8; \
    BUF[dd*2]   = *(const bf16x8*)(vth + voff); \
    BUF[dd*2+1] = *(const bf16x8*)(vtl + voff); \
  } }
#define VPV(G, BUF) { \
  const int kst_ = (G) >> 2, dp_ = (G) & 3; \
  _Pragma("unroll") \
  for (int dd = 0; dd < 2; dd++){ \
    int dn_ = dp_*2 + dd; \
    o[dn_] = mfma16(pah[kst_], BUF[dd*2+1], o[dn_]); \
    o[dn_] = mfma16(pal[kst_], BUF[dd*2],   o[dn_]); \
    o[dn_] = mfma16(pah[kst_], BUF[dd*2],   o[dn_]); \
  } }

__global__ __launch_bounds__(256,2) void k_attn(const unsigned short* __restrict__ qbh,
                                                const unsigned short* __restrict__ qbl,
                                                const unsigned short* __restrict__ kbh,
                                                const unsigned short* __restrict__ kbl,
                                                const unsigned short* __restrict__ vth,
                                                const unsigned short* __restrict__ vtl,
                                                unsigned short* __restrict__ abh,
                                                unsigned short* __restrict__ abl)
{
  __shared__ char ldsK[2][2][16384];   // [buf][hi/lo][64 rows x 256B]
  const int b   = blockIdx.x;          // 0..511
  const int xcd = b & 7, kk = xcd >> 1;
  const int s_  = ((b >> 3) << 1) | (xcd & 1);       // 0..127
  const int h   = kk*8 + (s_ >> 4);                  // head
  const int p   = s_ & 15;                           // pair index 0..15
  const int hk  = kk;
  const int tid = threadIdx.x;
  const int wv  = tid >> 6, lane = tid & 63;
  const int l15 = lane & 15, g16 = lane >> 4;
  const float sc = 0.08838834764831845f; // 1/sqrt(128)

  long gb[4];
  #pragma unroll
  for (int i = 0; i < 4; i++){
    int srow = i*16 + (tid >> 4);
    int c = (tid & 15) ^ (srow & 7);
    gb[i] = ((long)srow*NKV_ + hk)*D_ + c*8;
  }

  for (int ph = 0; ph < 2; ph++){
    const int qt  = ph ? p : (31 - p);
    const int q0  = qt*64 + wv*16;
    const int ntB = qt + 1;

    bf16x8 qfh[4], qfl[4];
    {
      long qoff = ((long)(q0 + l15)*NQ_ + h)*D_ + g16*8;
      #pragma unroll
      for (int ks = 0; ks < 4; ks++){
        qfh[ks] = *(const bf16x8*)(qbh + qoff + ks*32);
        qfl[ks] = *(const bf16x8*)(qbl + qoff + ks*32);
      }
    }

    f32x4 zz = {0.f,0.f,0.f,0.f};
    f32x4 o[8];
    #pragma unroll
    for (int dn = 0; dn < 8; dn++) o[dn] = zz;
    float m_run = -1e30f, l_run = 0.f;

    __syncthreads();   // previous phase's LDS reads complete before restaging
    #pragma unroll
    for (int i = 0; i < 4; i++){
      __builtin_amdgcn_global_load_lds((const AS1 int*)(kbh + gb[i]),
          (AS3 int*)((AS3 char*)&ldsK[0][0][0] + i*4096 + tid*16), 16, 0, 0);
      __builtin_amdgcn_global_load_lds((const AS1 int*)(kbl + gb[i]),
          (AS3 int*)((AS3 char*)&ldsK[0][1][0] + i*4096 + tid*16), 16, 0, 0);
    }

    for (int t = 0; t < ntB; t++){
      __syncthreads();                       // drains vmcnt: tile t resident
      const int kv0 = t*64;
      if (t+1 < ntB){
        long kadd = (long)(t+1)*64*NKV_*D_;
        int nb = (t+1) & 1;
        #pragma unroll
        for (int i = 0; i < 4; i++){
          __builtin_amdgcn_global_load_lds((const AS1 int*)(kbh + gb[i] + kadd),
              (AS3 int*)((AS3 char*)&ldsK[nb][0][0] + i*4096 + tid*16), 16, 0, 0);
          __builtin_amdgcn_global_load_lds((const AS1 int*)(kbl + gb[i] + kadd),
              (AS3 int*)((AS3 char*)&ldsK[nb][1][0] + i*4096 + tid*16), 16, 0, 0);
        }
      }
      {
        const char* Kh = &ldsK[t & 1][0][0];
        const char* Kl = &ldsK[t & 1][1][0];
        f32x4 sA[4];
        #pragma unroll
        for (int sub = 0; sub < 4; sub++) sA[sub] = zz;
        __builtin_amdgcn_s_setprio(1);
        #pragma unroll
        for (int sub = 0; sub < 4; sub++){
          int row = sub*16 + l15;
          int rsw = (row & 7) << 4;
          #pragma unroll
          for (int ks = 0; ks < 4; ks++){
            bf16x8 kh = *(const bf16x8*)(Kh + row*256 + (((ks*4 + g16)*16) ^ rsw));
            bf16x8 kl = *(const bf16x8*)(Kl + row*256 + (((ks*4 + g16)*16) ^ rsw));
            sA[sub] = mfma16(kh, qfl[ks], sA[sub]);
            sA[sub] = mfma16(kl, qfh[ks], sA[sub]);
            sA[sub] = mfma16(kh, qfh[ks], sA[sub]);
          }
        }
        __builtin_amdgcn_s_setprio(0);
        bf16x8 vA[4], vB[4];
        VISSUE(0, vA);
        {
          int qrow = q0 + l15;
          float mt = -1e30f;
          #pragma unroll
          for (int sub = 0; sub < 4; sub++)
            #pragma unroll
            for (int r = 0; r < 4; r++){
              int kva = kv0 + sub*16 + g16*4 + r;
              float v = sA[sub][r]*sc;
              if (kva > qrow) v = -1e30f;
              sA[sub][r] = v;
              mt = fmaxf(mt, v);
            }
          mt = fmaxf(mt, __shfl_xor(mt,16));
          mt = fmaxf(mt, __shfl_xor(mt,32));
          float mnew = fmaxf(m_run, mt);
          float corr = __expf(m_run - mnew);
          float ps = 0.f;
          #pragma unroll
          for (int sub = 0; sub < 4; sub++)
            #pragma unroll
            for (int r = 0; r < 4; r++){
              float e = __expf(sA[sub][r] - mnew);
              sA[sub][r] = e;
              ps += e;
            }
          ps += __shfl_xor(ps,16);
          ps += __shfl_xor(ps,32);
          l_run = l_run*corr + ps;
          m_run = mnew;
          #pragma unroll
          for (int r = 0; r < 4; r++){
            float cr = __shfl(corr, g16*4 + r);
            #pragma unroll
            for (int dn = 0; dn < 8; dn++) o[dn][r] *= cr;
          }
        }
        bf16x8 pah[2], pal[2];
        #pragma unroll
        for (int kst = 0; kst < 2; kst++){
          f32x4 s0 = sA[2*kst], s1 = sA[2*kst+1];
          i32x4 pkh, pkl;
          #pragma unroll
          for (int d = 0; d < 4; d++){
            const int e0 = 2*d, e1 = 2*d+1;
            int src0 = (((2*g16 + (e0>>2)) & 3) << 4) | l15;
            int src1 = (((2*g16 + (e1>>2)) & 3) << 4) | l15;
            float a0t = __shfl(s0[e0&3], src0), a1t = __shfl(s1[e0&3], src0);
            float b0t = __shfl(s0[e1&3], src1), b1t = __shfl(s1[e1&3], src1);
            float va = (g16 >= 2) ? a1t : a0t;
            float vb = (g16 >= 2) ? b1t : b0t;
            HL r = packsplit(va, vb);
            pkh[d] = r.h; pkl[d] = r.l;
          }
          pah[kst] = __builtin_bit_cast(bf16x8, pkh);
          pal[kst] = __builtin_bit_cast(bf16x8, pkl);
        }
        VISSUE(1, vB);
        __builtin_amdgcn_s_setprio(1);
        VPV(0, vA); VISSUE(2, vA);
        VPV(1, vB); VISSUE(3, vB);
        VPV(2, vA); VISSUE(4, vA);
        VPV(3, vB); VISSUE(5, vB);
        VPV(4, vA); VISSUE(6, vA);
        VPV(5, vB); VISSUE(7, vB);
        VPV(6, vA);
        VPV(7, vB);
        __builtin_amdgcn_s_setprio(0);
      }
    }

    {
      float linv = 1.0f / l_run;
      #pragma unroll
      for (int r = 0; r < 4; r++){
        float lr = __shfl(linv, g16*4 + r);
        long row = q0 + g16*4 + r;
        #pragma unroll
        for (int dn = 0; dn < 8; dn++){
          float v = o[dn][r]*lr;
          unsigned hi = f2bf_u(v);
          long idx = row*(NQ_*D_) + h*D_ + dn*16 + l15;
          abh[idx] = (unsigned short)hi;
          abl[idx] = (unsigned short)f2bf_u(v - bf2f(hi));
        }
      }
    }
  }
}

// ---------------- Split-precision GEMM (A hi/lo bf16 x B fp32) ---------------
// MODE 0: qkv proj (store fp32)   MODE 1: wo proj (+residual, store fp32)
struct SA {
  const unsigned short* Ah;
  const unsigned short* Al;
  const float* B;
  int lda, ldb, K, ldc;
  float* Cf;
  const float* add;
};

template<int MODE>
__global__ __launch_bounds__(256,2) void k_gs(SA ga)
{
  __shared__ unsigned short ldsAh[128*64];
  __shared__ unsigned short ldsAl[128*64];
  __shared__ unsigned short ldsBh[8*128*8];
  __shared__ unsigned short ldsBl[8*128*8];
  const int tid = threadIdx.x;
  const int lane = tid & 63;
  const int wv = tid >> 6;
  const int wm = (wv >> 1)*64, wn = (wv & 1)*64;
  const int l15 = lane & 15, g16 = lane >> 4;

  const long m0 = (long)blockIdx.y * 128;
  const long n0 = (long)blockIdx.x * 128;

  long aoff[4];
  #pragma unroll
  for (int i = 0; i < 4; i++){
    int chunk = tid + i*256;
    int m = chunk >> 3, c = chunk & 7;
    aoff[i] = (m0 + m) * (long)ga.lda + c*8;
  }
  const float* brow = ga.B + n0 + (long)((tid >> 5)*8) * ga.ldb + (tid & 31)*4;

  f32x4 zz = {0.f,0.f,0.f,0.f};
  f32x4 acc[4][4];
  #pragma unroll
  for (int i = 0; i < 4; i++)
    #pragma unroll
    for (int j = 0; j < 4; j++) acc[i][j] = zz;

  i32x4 pva[4], pvl[4];
  float4 pb[8];
  #pragma unroll
  for (int i = 0; i < 4; i++){
    pva[i] = *(const i32x4*)(ga.Ah + aoff[i]);
    pvl[i] = *(const i32x4*)(ga.Al + aoff[i]);
  }
  #pragma unroll
  for (int r = 0; r < 8; r++) pb[r] = *(const float4*)(brow + (long)r * ga.ldb);

  for (int kt = 0; kt < ga.K; kt += 64){
    __syncthreads();
    #pragma unroll
    for (int i = 0; i < 4; i++){
      int chunk = tid + i*256;
      int m = chunk >> 3, c = chunk & 7;
      int sw = (c*16) ^ ((m & 7) << 4);
      *(i32x4*)((char*)ldsAh + m*128 + sw) = pva[i];
      *(i32x4*)((char*)ldsAl + m*128 + sw) = pvl[i];
    }
    {
      i32x4 ph0, ph1, ph2, ph3, pl0, pl1, pl2, pl3;
      #pragma unroll
      for (int r = 0; r < 8; r += 2){
        float4 va = pb[r];
        float4 vb = pb[r+1];
        int d = r >> 1;
        HL rx = packsplit(va.x, vb.x); ph0[d] = rx.h; pl0[d] = rx.l;
        HL ry = packsplit(va.y, vb.y); ph1[d] = ry.h; pl1[d] = ry.l;
        HL rz = packsplit(va.z, vb.z); ph2[d] = rz.h; pl2[d] = rz.l;
        HL rw = packsplit(va.w, vb.w); ph3[d] = rw.h; pl3[d] = rw.l;
      }
      int kbb = tid >> 5, nb = (tid & 31)*4;
      long bo = ((long)kbb*128 + nb) << 4;
      char* bph = (char*)ldsBh + bo;
      char* bpl = (char*)ldsBl + bo;
      *(i32x4*)(bph)      = ph0;  *(i32x4*)(bpl)      = pl0;
      *(i32x4*)(bph + 16) = ph1;  *(i32x4*)(bpl + 16) = pl1;
      *(i32x4*)(bph + 32) = ph2;  *(i32x4*)(bpl + 32) = pl2;
      *(i32x4*)(bph + 48) = ph3;  *(i32x4*)(bpl + 48) = pl3;
    }
    __syncthreads();
    if (kt + 64 < ga.K){
      #pragma unroll
      for (int i = 0; i < 4; i++){
        pva[i] = *(const i32x4*)(ga.Ah + aoff[i] + kt + 64);
        pvl[i] = *(const i32x4*)(ga.Al + aoff[i] + kt + 64);
      }
      #pragma unroll
      for (int r = 0; r < 8; r++) pb[r] = *(const float4*)(brow + (long)(kt + 64 + r) * ga.ldb);
    }
    #pragma unroll
    for (int ks = 0; ks < 2; ks++){
      bf16x8 afh[4], afl[4], bfh[4], bfl[4];
      #pragma unroll
      for (int i = 0; i < 4; i++){
        int m = wm + i*16 + l15;
        int sw = (ks*64 + g16*16) ^ ((m & 7) << 4);
        afh[i] = *(const bf16x8*)((const char*)ldsAh + m*128 + sw);
        afl[i] = *(const bf16x8*)((const char*)ldsAl + m*128 + sw);
      }
      #pragma unroll
      for (int j = 0; j < 4; j++){
        int n = wn + j*16 + l15;
        long bo = ((long)(ks*4 + g16)*128 + n) << 4;
        bfh[j] = *(const bf16x8*)((const char*)ldsBh + bo);
        bfl[j] = *(const bf16x8*)((const char*)ldsBl + bo);
      }
      #pragma unroll
      for (int i = 0; i < 4; i++)
        #pragma unroll
        for (int j = 0; j < 4; j++){
          acc[i][j] = mfma16(afh[i], bfl[j], acc[i][j]);
          acc[i][j] = mfma16(afl[i], bfh[j], acc[i][j]);
          acc[i][j] = mfma16(afh[i], bfh[j], acc[i][j]);
        }
    }
  }

  #pragma unroll
  for (int i = 0; i < 4; i++){
    #pragma unroll
    for (int j = 0; j < 4; j++){
      #pragma unroll
      for (int r = 0; r < 4; r++){
        float v = acc[i][j][r];
        long grow = m0 + wm + i*16 + g16*4 + r;
        long gcol = n0 + wn + j*16 + l15;
        long idx = grow * ga.ldc + gcol;
        if (MODE == 0) ga.Cf[idx] = v;
        else           ga.Cf[idx] = v + ga.add[idx];
      }
    }
  }
}

// ---------------- Router logits: split-bf16 GEMM M=2048 N=64 K=2048 ----------
__global__ __launch_bounds__(256,2) void k_logits(const unsigned short* __restrict__ Ah,
                                                  const unsigned short* __restrict__ Al,
                                                  const float* __restrict__ B,
                                                  float* __restrict__ logits)
{
  __shared__ unsigned short ldsAh[256*64];   // 32 KB
  __shared__ unsigned short ldsAl[256*64];   // 32 KB
  __shared__ unsigned short ldsBh[8*64*8];   // 8 KB
  __shared__ unsigned short ldsBl[8*64*8];   // 8 KB
  const int tid = threadIdx.x, lane = tid & 63, wv = tid >> 6;
  const int l15 = lane & 15, g16 = lane >> 4;
  const long m0 = (long)blockIdx.x * 256;

  long aoff[8];
  #pragma unroll
  for (int i = 0; i < 8; i++){
    int chunk = tid + i*256;
    int m = chunk >> 3, c = chunk & 7;
    int csw = c ^ (m & 7);
    aoff[i] = (m0 + m) * (long)H_ + csw*8;
  }
  const float* brow = B + (long)((tid >> 5)*8) * E_ + (tid & 31)*2;

  f32x4 zz = {0.f,0.f,0.f,0.f};
  f32x4 acc[4][4];
  #pragma unroll
  for (int i = 0; i < 4; i++)
    #pragma unroll
    for (int j = 0; j < 4; j++) acc[i][j] = zz;

  float2 pb[8];
  #pragma unroll
  for (int r = 0; r < 8; r++) pb[r] = *(const float2*)(brow + (long)r * E_);

  for (int kt = 0; kt < H_; kt += 64){
    __syncthreads();
    #pragma unroll
    for (int i = 0; i < 8; i++){
      __builtin_amdgcn_global_load_lds((const AS1 int*)(Ah + aoff[i] + kt),
          (AS3 int*)((AS3 char*)ldsAh + i*4096 + tid*16), 16, 0, 0);
      __builtin_amdgcn_global_load_lds((const AS1 int*)(Al + aoff[i] + kt),
          (AS3 int*)((AS3 char*)ldsAl + i*4096 + tid*16), 16, 0, 0);
    }
    {
      i32x4 p0h, p0l, p1h, p1l;
      #pragma unroll
      for (int r = 0; r < 8; r += 2){
        int d = r >> 1;
        HL rx = packsplit(pb[r].x, pb[r+1].x); p0h[d] = rx.h; p0l[d] = rx.l;
        HL ry = packsplit(pb[r].y, pb[r+1].y); p1h[d] = ry.h; p1l[d] = ry.l;
      }
      int kbb = tid >> 5, nb = (tid & 31)*2;
      long bo = ((long)kbb*64 + nb) << 4;
      *(i32x4*)((char*)ldsBh + bo)      = p0h;
      *(i32x4*)((char*)ldsBh + bo + 16) = p1h;
      *(i32x4*)((char*)ldsBl + bo)      = p0l;
      *(i32x4*)((char*)ldsBl + bo + 16) = p1l;
    }
    __syncthreads();
    if (kt + 64 < H_){
      #pragma unroll
      for (int r = 0; r < 8; r++) pb[r] = *(const float2*)(brow + (long)(kt + 64 + r) * E_);
    }
    #pragma unroll
    for (int ks = 0; ks < 2; ks++){
      bf16x8 afh[4], afl[4], bfh[4], bfl[4];
      #pragma unroll
      for (int i = 0; i < 4; i++){
        int m = wv*64 + i*16 + l15;
        int sw = (ks*64 + g16*16) ^ ((m & 7) << 4);
        afh[i] = *(const bf16x8*)((const char*)ldsAh + m*128 + sw);
        afl[i] = *(const bf16x8*)((const char*)ldsAl + m*128 + sw);
      }
      #pragma unroll
      for (int j = 0; j < 4; j++){
        int n = j*16 + l15;
        long bo = ((long)(ks*4 + g16)*64 + n) << 4;
        bfh[j] = *(const bf16x8*)((const char*)ldsBh + bo);
        bfl[j] = *(const bf16x8*)((const char*)ldsBl + bo);
      }
      #pragma unroll
      for (int i = 0; i < 4; i++)
        #pragma unroll
        for (int j = 0; j < 4; j++){
          acc[i][j] = mfma16(afh[i], bfl[j], acc[i][j]);
          acc[i][j] = mfma16(afl[i], bfh[j], acc[i][j]);
          acc[i][j] = mfma16(afh[i], bfh[j], acc[i][j]);
        }
    }
  }

  #pragma unroll
  for (int i = 0; i < 4; i++)
    #pragma unroll
    for (int j = 0; j < 4; j++)
      #pragma unroll
      for (int r = 0; r < 4; r++){
        long row = m0 + wv*64 + i*16 + g16*4 + r;
        logits[row*E_ + j*16 + l15] = acc[i][j][r];
      }
}

// ---------------- Router part 2: softmax + top8 from logits ------------------
__global__ __launch_bounds__(64) void k_router2(const float* __restrict__ logits,
                                                int* __restrict__ tidx,
                                                float* __restrict__ twv)
{
  __shared__ int   ti[8];
  __shared__ float tv[8];
  const int t = blockIdx.x, lane = threadIdx.x;
  float acc = logits[(long)t*E_ + lane];
  float mx = acc;
  #pragma unroll
  for (int o = 32; o >= 1; o >>= 1) mx = fmaxf(mx, __shfl_xor(mx, o));
  float p = __expf(acc - mx);
  float sm = p;
  #pragma unroll
  for (int o = 32; o >= 1; o >>= 1) sm += __shfl_xor(sm, o);
  p /= sm;
  float cur = p, wsum = 0.f;
  #pragma unroll
  for (int j = 0; j < 8; j++){
    float v = cur; int ix = lane;
    #pragma unroll
    for (int o = 1; o < 64; o <<= 1){
      float ov = __shfl_xor(v, o); int oi = __shfl_xor(ix, o);
      if (ov > v || (ov == v && oi < ix)){ v = ov; ix = oi; }
    }
    if (lane == ix) cur = -1.f;
    wsum += v;
    if (lane == 0){ ti[j] = ix; tv[j] = v; }
  }
  __syncthreads();
  if (lane < 8){
    tidx[t*TK_ + lane] = ti[lane];
    twv [t*TK_ + lane] = tv[lane] / wsum;
  }
}

// ---------------- Plain bf16 GEMM (MoE), M=256 x N=64 ------------------------
// One m-block covers an expert's whole token set -> cold B panel read ONCE.
// Wave = 64 rows x 64 staged cols, acc[4][4]. B staging = float2[8] (16 regs).
// MODE 2: gate+up fused (silu epilogue). MODE 3: down (atomic scatter).
// A staged via global_load_lds (pre-swizzled source); (256,3) => 3 blocks/CU.
struct GA {
  const unsigned short* A;
  const float* B;
  const float* B2;
  int lda, ldb, K, ldc;
  unsigned short* Cb;
  const int* rowidx;
  const float* wslot;
  const int* counts;
  float* outp;
};

template<int MODE>
__global__ __launch_bounds__(256,3) void k_gemm(GA ga)
{
  __shared__ unsigned short ldsA[256*64];   // 32 KB
  __shared__ unsigned short ldsB[8*64*8];   // 8 KB
  const int tid = threadIdx.x;
  const int lane = tid & 63;
  const int wv = tid >> 6;
  const int l15 = lane & 15, g16 = lane >> 4;

  long m0 = (long)blockIdx.y * 256;
  long n0 = 0;
  const unsigned short* A = ga.A;
  const int* rowmap = nullptr;
  int e = blockIdx.z, count = ga.counts[e];
  if ((int)m0 >= count) return;

  const float* bbase;
  {
    int c2 = (tid & 31) * 2;
    if (MODE == 2){
      n0 = (long)blockIdx.x * 32;
      rowmap = ga.rowidx + e * CAP_;
      if (c2 < 32) bbase = ga.B  + (long)e * H_ * I_ + n0 + c2;        // wg
      else         bbase = ga.B2 + (long)e * H_ * I_ + n0 + (c2 - 32); // wu
    } else {
      n0 = (long)blockIdx.x * 64;
      bbase = ga.B + (long)e * I_ * H_ + n0 + c2;
      A = ga.A + (long)e * CAP_ * I_;
    }
  }

  const unsigned short* arow[8];
  #pragma unroll
  for (int i = 0; i < 8; i++){
    int chunk = tid + i*256;
    int m = chunk >> 3, c = chunk & 7;
    int csw = c ^ (m & 7);
    int s = (int)m0 + m; if (s > count - 1) s = count - 1;
    long row = (MODE == 2) ? (long)rowmap[s] : (long)s;
    arow[i] = A + row * (long)ga.lda + csw*8;
  }
  const float* brow = bbase + (long)((tid >> 5)*8) * ga.ldb;

  f32x4 zz = {0.f,0.f,0.f,0.f};
  f32x4 acc[4][4];
  #pragma unroll
  for (int i = 0; i < 4; i++)
    #pragma unroll
    for (int j = 0; j < 4; j++) acc[i][j] = zz;

  float2 pb[8];
  #pragma unroll
  for (int r = 0; r < 8; r++) pb[r] = *(const float2*)(brow + (long)r * ga.ldb);

  for (int kt = 0; kt < ga.K; kt += 64){
    __syncthreads();
    #pragma unroll
    for (int i = 0; i < 8; i++){
      __builtin_amdgcn_global_load_lds((const AS1 int*)(arow[i] + kt),
          (AS3 int*)((AS3 char*)ldsA + i*4096 + tid*16), 16, 0, 0);
    }
    {
      i32x4 p0, p1;
      #pragma unroll
      for (int r = 0; r < 8; r += 2){
        int d = r >> 1;
        p0[d] = (int)(f2bf_u(pb[r].x) | (f2bf_u(pb[r+1].x) << 16));
        p1[d] = (int)(f2bf_u(pb[r].y) | (f2bf_u(pb[r+1].y) << 16));
      }
      int kbb = tid >> 5, nb = (tid & 31)*2;
      char* bp = (char*)ldsB + (((long)kbb*64 + nb) << 4);
      *(i32x4*)(bp)      = p0;
      *(i32x4*)(bp + 16) = p1;
    }
    __syncthreads();
    if (kt + 64 < ga.K){
      #pragma unroll
      for (int r = 0; r < 8; r++) pb[r] = *(const float2*)(brow + (long)(kt + 64 + r) * ga.ldb);
    }
    #pragma unroll
    for (int ks = 0; ks < 2; ks++){
      bf16x8 af[4], bfv[4];
      #pragma unroll
      for (int i = 0; i < 4; i++){
        int m = wv*64 + i*16 + l15;
        af[i] = *(const bf16x8*)((const char*)ldsA + m*128 + ((ks*64 + g16*16) ^ ((m & 7) << 4)));
      }
      #pragma unroll
      for (int j = 0; j < 4; j++){
        int n = j*16 + l15;
        bfv[j] = *(const bf16x8*)((const char*)ldsB + (((long)(ks*4 + g16)*64 + n) << 4));
      }
      #pragma unroll
      for (int i = 0; i < 4; i++)
        #pragma unroll
        for (int j = 0; j < 4; j++)
          acc[i][j] = mfma16(af[i], bfv[j], acc[i][j]);
    }
  }

  if (MODE == 2){
    #pragma unroll
    for (int i = 0; i < 4; i++){
      #pragma unroll
      for (int jj = 0; jj < 2; jj++){
        #pragma unroll
        for (int r = 0; r < 4; r++){
          float g = acc[i][jj][r];
          float u = acc[i][jj+2][r];
          float actv = g / (1.f + __expf(-g)) * u;
          int grow = (int)m0 + wv*64 + i*16 + g16*4 + r;
          if (grow < count)
            ga.Cb[((long)e*CAP_ + grow)*I_ + n0 + jj*16 + l15] = (unsigned short)f2bf_u(actv);
        }
      }
    }
  } else {
    #pragma unroll
    for (int i = 0; i < 4; i++){
      #pragma unroll
      for (int j = 0; j < 4; j++){
        #pragma unroll
        for (int r = 0; r < 4; r++){
          float v = acc[i][j][r];
          int grow = (int)m0 + wv*64 + i*16 + g16*4 + r;
          long gcol = n0 + j*16 + l15;
          if (grow < count){
            float ww = ga.wslot[e*CAP_ + grow];
            int tk = ga.rowidx[e*CAP_ + grow];
            atomicAdd(ga.outp + (long)tk*H_ + gcol, v*ww);
          }
        }
      }
    }
  }
}

// ---------------- Capacity scan (reference cumsum order) ---------------------
__global__ __launch_bounds__(64) void k_route(const int* __restrict__ tidx,
                                              const float* __restrict__ twv,
                                              int* __restrict__ rowi,
                                              float* __restrict__ wsl,
                                              int* __restrict__ cnts)
{
  const int e = blockIdx.x, lane = threadIdx.x;
  int run = 0;
  for (int s0 = 0; s0 < T_*TK_; s0 += 64){
    int s = s0 + lane;
    int idx = tidx[s];
    bool m = (idx == e);
    unsigned long long mk = __ballot(m);
    int pre = __popcll(mk & ((1ull << lane) - 1ull));
    int pos = run + pre;
    if (m && pos < CAP_){
      rowi[e*CAP_ + pos] = s >> 3;
      wsl [e*CAP_ + pos] = twv[s];
    }
    run += __popcll(mk);
  }
  if (lane == 0) cnts[e] = (run < CAP_) ? run : CAP_;
}

// ---------------- launch -----------------------------------------------------
extern "C" void kernel_launch(void* const* d_in, const int* in_sizes, int n_in,
                              void* d_out, int out_size, void* d_ws, size_t ws_size,
                              hipStream_t stream)
{
  (void)in_sizes; (void)n_in; (void)out_size; (void)ws_size;
  const float* x    = (const float*)d_in[0];
  const int*   pos  = (const int*)d_in[1];
  const float* wqkv = (const float*)d_in[2];
  const float* wo   = (const float*)d_in[3];
  const float* qnw  = (const float*)d_in[4];
  const float* knw  = (const float*)d_in[5];
  const float* ln1  = (const float*)d_in[6];
  const float* ln2  = (const float*)d_in[7];
  const float* gwt  = (const float*)d_in[8];
  const float* wg   = (const float*)d_in[9];
  const float* wu   = (const float*)d_in[10];
  const float* wd   = (const float*)d_in[11];
  float* out = (float*)d_out;

  char* ws = (char*)d_ws;
  size_t off = 0;
  auto alloc = [&](size_t b)->void*{ void* p = ws + off; off += (b + 255) & ~(size_t)255; return p; };

  unsigned short* hbh = (unsigned short*)alloc((size_t)T_*H_*2);
  unsigned short* hbl = (unsigned short*)alloc((size_t)T_*H_*2);
  float* qkv          = (float*)alloc((size_t)T_*QKVW_*4);
  float* cosb         = (float*)alloc((size_t)T_*64*4);
  float* sinb         = (float*)alloc((size_t)T_*64*4);
  unsigned short* qbh = (unsigned short*)alloc((size_t)T_*NQ_*D_*2);
  unsigned short* qbl = (unsigned short*)alloc((size_t)T_*NQ_*D_*2);
  unsigned short* kbh = (unsigned short*)alloc((size_t)T_*NKV_*D_*2);
  unsigned short* kbl = (unsigned short*)alloc((size_t)T_*NKV_*D_*2);
  unsigned short* vth = (unsigned short*)alloc((size_t)NKV_*D_*T_*2);
  unsigned short* vtl = (unsigned short*)alloc((size_t)NKV_*D_*T_*2);
  unsigned short* abh = (unsigned short*)alloc((size_t)T_*NQ_*D_*2);
  unsigned short* abl = (unsigned short*)alloc((size_t)T_*NQ_*D_*2);
  float* x2           = (float*)alloc((size_t)T_*H_*4);
  unsigned short* h2b = (unsigned short*)alloc((size_t)T_*H_*2);
  unsigned short* h2l = (unsigned short*)alloc((size_t)T_*H_*2);
  float* lgt          = (float*)alloc((size_t)T_*E_*4);
  int* tidx           = (int*)alloc((size_t)T_*TK_*4);
  float* twv          = (float*)alloc((size_t)T_*TK_*4);
  int* rowi           = (int*)alloc((size_t)E_*CAP_*4);
  float* wsl          = (float*)alloc((size_t)E_*CAP_*4);
  int* cnts           = (int*)alloc((size_t)E_*4);
  unsigned short* gu  = (unsigned short*)alloc((size_t)E_*CAP_*I_*2);  // fused act

  k_rms<<<T_, 256, 0, stream>>>(x, ln1, hbh, hbl, nullptr);
  k_ropetab<<<T_, 64, 0, stream>>>(pos, cosb, sinb);
  {
    SA a{}; a.Ah = hbh; a.Al = hbl; a.B = wqkv; a.lda = H_; a.ldb = QKVW_; a.K = H_; a.ldc = QKVW_; a.Cf = qkv;
    k_gs<0><<<dim3(QKVW_/128, T_/128), 256, 0, stream>>>(a);
  }
  k_qknorm<<<T_*36/4, 256, 0, stream>>>(qkv, qnw, knw, cosb, sinb, qbh, qbl, kbh, kbl);
  k_vtrans<<<dim3(T_/64, NKV_), 256, 0, stream>>>(qkv, vth, vtl);
  k_attn<<<512, 256, 0, stream>>>(qbh, qbl, kbh, kbl, vth, vtl, abh, abl);
  {
    SA a{}; a.Ah = abh; a.Al = abl; a.B = wo; a.lda = NQ_*D_; a.ldb = H_; a.K = NQ_*D_; a.ldc = H_;
    a.Cf = x2; a.add = x;
    k_gs<1><<<dim3(H_/128, T_/128), 256, 0, stream>>>(a);
  }
  k_rms<<<T_, 256, 0, stream>>>(x2, ln2, h2b, h2l, out);   // h2 hi/lo + out = x2
  k_logits<<<T_/256, 256, 0, stream>>>(h2b, h2l, gwt, lgt);
  k_router2<<<T_, 64, 0, stream>>>(lgt, tidx, twv);
  k_route<<<E_, 64, 0, stream>>>(tidx, twv, rowi, wsl, cnts);
  {
    GA a{}; a.A = h2b; a.B = wg; a.B2 = wu; a.lda = H_; a.ldb = I_; a.K = H_;
    a.Cb = gu; a.rowidx = rowi; a.counts = cnts;
    k_gemm<2><<<dim3(24, 2, E_), 256, 0, stream>>>(a);
  }
  {
    GA a{}; a.A = gu; a.B = wd; a.lda = I_; a.ldb = H_; a.K = I_;
    a.counts = cnts; a.rowidx = rowi; a.wslot = wsl; a.outp = out;
    k_gemm<3><<<dim3(32, 2, E_), 256, 0, stream>>>(a);
  }
}